// Round 1
// baseline (297.908 us; speedup 1.0000x reference)
//
#include <hip/hip_runtime.h>

// EncoderLayer: pre-norm MHA + FFN, B=2 S=2048 D=768 H=12 DFF=2048, fp32 I/O,
// bf16 MFMA internals. Pipeline:
//   cvt weights->bf16, LN1, QKV-GEMM(fused N=2304), flash-attn, Wo-GEMM+res,
//   LN2, FFN1-GEMM+relu, FFN2-GEMM+res -> d_out
#define SS   2048
#define DD   768
#define HH   12
#define DFFF 2048
#define BSR  4096      // B*S
#define QKV_LD 2304

typedef __attribute__((ext_vector_type(8))) short bf16x8;
typedef __attribute__((ext_vector_type(4))) float f32x4;

__device__ __forceinline__ unsigned short f2b(float f) {
  union { float f; unsigned u; } x; x.f = f;
  unsigned r = (x.u + 0x7FFFu + ((x.u >> 16) & 1u)) >> 16;
  return (unsigned short)r;
}

__device__ __forceinline__ void gload_lds16(const void* g, void* l) {
  __builtin_amdgcn_global_load_lds(
      (const __attribute__((address_space(1))) unsigned int*)g,
      (__attribute__((address_space(3))) unsigned int*)l,
      16, 0, 0);
}

// ---------------- fp32 -> bf16 convert (4 elems/thread) ----------------
__global__ __launch_bounds__(256) void cvt_bf16_k(const float* __restrict__ src,
                                                  unsigned short* __restrict__ dst) {
  long i = ((long)blockIdx.x * 256 + threadIdx.x) * 4;
  float4 v = *(const float4*)&src[i];
  uint2 pk;
  pk.x = (unsigned)f2b(v.x) | ((unsigned)f2b(v.y) << 16);
  pk.y = (unsigned)f2b(v.z) | ((unsigned)f2b(v.w) << 16);
  *(uint2*)&dst[i] = pk;
}

__global__ __launch_bounds__(256) void concat3_k(const float* __restrict__ a,
                                                 const float* __restrict__ b,
                                                 const float* __restrict__ c,
                                                 float* __restrict__ out) {
  int i = blockIdx.x * 256 + threadIdx.x;
  if (i < 768) out[i] = a[i];
  else if (i < 1536) out[i] = b[i - 768];
  else if (i < 2304) out[i] = c[i - 1536];
}

// ---------------- LayerNorm (torch semantics: ddof=1, eps on std) -------
__global__ __launch_bounds__(64) void layernorm_k(const float* __restrict__ x,
                                                  const float* __restrict__ alpha,
                                                  const float* __restrict__ beta,
                                                  unsigned short* __restrict__ outb) {
  const int row = blockIdx.x, lane = threadIdx.x;
  const float* xr = x + (long)row * DD;
  float4 v[3];
#pragma unroll
  for (int g = 0; g < 3; ++g) v[g] = *(const float4*)&xr[lane * 12 + g * 4];
  float sum = 0.f;
#pragma unroll
  for (int g = 0; g < 3; ++g) sum += v[g].x + v[g].y + v[g].z + v[g].w;
#pragma unroll
  for (int off = 1; off < 64; off <<= 1) sum += __shfl_xor(sum, off);
  float mu = sum * (1.0f / 768.0f);
  float ss = 0.f;
#pragma unroll
  for (int g = 0; g < 3; ++g) {
    float a0 = v[g].x - mu, a1 = v[g].y - mu, a2 = v[g].z - mu, a3 = v[g].w - mu;
    ss += a0 * a0 + a1 * a1 + a2 * a2 + a3 * a3;
  }
#pragma unroll
  for (int off = 1; off < 64; off <<= 1) ss += __shfl_xor(ss, off);
  float sd = sqrtf(ss * (1.0f / 767.0f));
  float inv = 1.0f / (sd + 1e-6f);
  unsigned short* orow = outb + (long)row * DD;
#pragma unroll
  for (int g = 0; g < 3; ++g) {
    float4 al = *(const float4*)&alpha[lane * 12 + g * 4];
    float4 be = *(const float4*)&beta[lane * 12 + g * 4];
    float o0 = al.x * (v[g].x - mu) * inv + be.x;
    float o1 = al.y * (v[g].y - mu) * inv + be.y;
    float o2 = al.z * (v[g].z - mu) * inv + be.z;
    float o3 = al.w * (v[g].w - mu) * inv + be.w;
    uint2 pk;
    pk.x = (unsigned)f2b(o0) | ((unsigned)f2b(o1) << 16);
    pk.y = (unsigned)f2b(o2) | ((unsigned)f2b(o3) << 16);
    *(uint2*)&orow[lane * 12 + g * 4] = pk;
  }
}

// ---------------- bf16 GEMM: C[M,N] = A[M,K] * W[N,K]^T (+bias,+res,relu) ----
// 128x128 tile, BK=64, 4 waves, global_load_lds staging (m97 structure).
template <bool RELU, bool RES, bool OUTB>
__global__ __launch_bounds__(256, 2) void gemm_bt(const unsigned short* __restrict__ A,
                                                  const unsigned short* __restrict__ W,
                                                  const float* __restrict__ bias,
                                                  const float* __restrict__ res,
                                                  void* __restrict__ outp,
                                                  int M, int N, int K) {
  __shared__ __align__(16) unsigned short As[128 * 64];
  __shared__ __align__(16) unsigned short Bs[128 * 64];
  const int t = threadIdx.x;
  const int lane = t & 63;
  const int w = t >> 6;
  const int wr = w >> 1, wc = w & 1;
  const int l15 = lane & 15, l4 = lane >> 4;
  const long brow = (long)blockIdx.y * 128;
  const long bcol = (long)blockIdx.x * 128;
  f32x4 acc[4][4] = {};
  const int r0 = t >> 3;        // 0..31
  const int c8 = (t & 7) * 8;   // 0..56

  for (int k0 = 0; k0 < K; k0 += 64) {
    __syncthreads();
#pragma unroll
    for (int p = 0; p < 4; ++p) {
      gload_lds16(&A[(brow + p * 32 + r0) * (long)K + k0 + c8],
                  (char*)As + p * 4096 + w * 1024);
      gload_lds16(&W[(bcol + p * 32 + r0) * (long)K + k0 + c8],
                  (char*)Bs + p * 4096 + w * 1024);
    }
    __syncthreads();
#pragma unroll
    for (int ks = 0; ks < 2; ++ks) {
      bf16x8 a[4], b[4];
#pragma unroll
      for (int m = 0; m < 4; ++m)
        a[m] = *(const bf16x8*)&As[(wr * 64 + m * 16 + l15) * 64 + ks * 32 + l4 * 8];
#pragma unroll
      for (int n = 0; n < 4; ++n)
        b[n] = *(const bf16x8*)&Bs[(wc * 64 + n * 16 + l15) * 64 + ks * 32 + l4 * 8];
#pragma unroll
      for (int m = 0; m < 4; ++m)
#pragma unroll
        for (int n = 0; n < 4; ++n)
          acc[m][n] = __builtin_amdgcn_mfma_f32_16x16x32_bf16(a[m], b[n], acc[m][n], 0, 0, 0);
    }
  }
  // epilogue: D[row][col], row=(lane>>4)*4+reg, col=lane&15 within 16x16 frag
#pragma unroll
  for (int n = 0; n < 4; ++n) {
    const long col = bcol + wc * 64 + n * 16 + l15;
    const float bv = bias[col];
#pragma unroll
    for (int m = 0; m < 4; ++m) {
      const long row0 = brow + wr * 64 + m * 16 + l4 * 4;
#pragma unroll
      for (int r = 0; r < 4; ++r) {
        float v = acc[m][n][r] + bv;
        if (RELU) v = fmaxf(v, 0.0f);
        long o = (row0 + r) * (long)N + col;
        if (RES) v += res[o];
        if (OUTB) ((unsigned short*)outp)[o] = f2b(v);
        else ((float*)outp)[o] = v;
      }
    }
  }
}

// --------- pull per-q value out of row-stat registers (stats for row q live
// --------- in lanes l>>4==q>>2 at reg q&3) ---------
__device__ __forceinline__ float redist16(const float v0, const float v1,
                                          const float v2, const float v3, int l15) {
  int src = (l15 >> 2) << 4;
  float f0 = __shfl(v0, src);
  float f1 = __shfl(v1, src);
  float f2 = __shfl(v2, src);
  float f3 = __shfl(v3, src);
  int rr = l15 & 3;
  return rr == 0 ? f0 : rr == 1 ? f1 : rr == 2 ? f2 : f3;
}

// ---------------- flash attention: one (b,h,64-q-tile) per block ----------
__global__ __launch_bounds__(256, 2) void attn_kernel(const unsigned short* __restrict__ qkv,
                                                      const int* __restrict__ mask,
                                                      unsigned short* __restrict__ ctx) {
  __shared__ __align__(16) unsigned short Vt[64 * 72];     // V^T [d][key], pad 72
  __shared__ __align__(16) unsigned short Pl[4][16 * 72];  // per-wave P [q][key]
  const int t = threadIdx.x, lane = t & 63, w = t >> 6;
  const int l15 = lane & 15, l4 = lane >> 4;
  const int qt = blockIdx.x, h = blockIdx.y, b = blockIdx.z;
  const long rowB = (long)b * SS;
  const int qrow = qt * 64 + w * 16;

  bf16x8 aq[2];
#pragma unroll
  for (int ks = 0; ks < 2; ++ks)
    aq[ks] = *(const bf16x8*)&qkv[(rowB + qrow + l15) * QKV_LD + h * 64 + ks * 32 + l4 * 8];

  f32x4 o[4] = {};
  float mrun0 = -1e30f, mrun1 = -1e30f, mrun2 = -1e30f, mrun3 = -1e30f;
  float ls0 = 0.f, ls1 = 0.f, ls2 = 0.f, ls3 = 0.f;

  for (int kb = 0; kb < 32; ++kb) {
    __syncthreads();
    // stage V transposed: Vt[d][key]
#pragma unroll
    for (int p = 0; p < 2; ++p) {
      int key = p * 32 + (t >> 3);
      int d0 = (t & 7) * 8;
      uint4 vv = *(const uint4*)&qkv[(rowB + kb * 64 + key) * QKV_LD + 1536 + h * 64 + d0];
      unsigned uu[4] = {vv.x, vv.y, vv.z, vv.w};
#pragma unroll
      for (int j = 0; j < 4; ++j) {
        Vt[(d0 + 2 * j) * 72 + key] = (unsigned short)(uu[j] & 0xffffu);
        Vt[(d0 + 2 * j + 1) * 72 + key] = (unsigned short)(uu[j] >> 16);
      }
    }
    __syncthreads();

    // scores S[q16][key64]
    f32x4 s[4] = {};
#pragma unroll
    for (int ks = 0; ks < 2; ++ks) {
#pragma unroll
      for (int cg = 0; cg < 4; ++cg) {
        bf16x8 bk = *(const bf16x8*)&qkv[(rowB + kb * 64 + cg * 16 + l15) * QKV_LD + 768 +
                                         h * 64 + ks * 32 + l4 * 8];
        s[cg] = __builtin_amdgcn_mfma_f32_16x16x32_bf16(aq[ks], bk, s[cg], 0, 0, 0);
      }
    }
    // scale + mask
#pragma unroll
    for (int cg = 0; cg < 4; ++cg) {
      float madd = mask[b * SS + kb * 64 + cg * 16 + l15] ? 0.f : -1e9f;
#pragma unroll
      for (int r = 0; r < 4; ++r) s[cg][r] = s[cg][r] * 0.125f + madd;
    }
    // online softmax row stats (row = l4*4 + r)
    float fac0, fac1, fac2, fac3;
    {
      float* mr[4] = {&mrun0, &mrun1, &mrun2, &mrun3};
      float* lsv[4] = {&ls0, &ls1, &ls2, &ls3};
      float* fc[4] = {&fac0, &fac1, &fac2, &fac3};
#pragma unroll
      for (int r = 0; r < 4; ++r) {
        float mx = fmaxf(fmaxf(s[0][r], s[1][r]), fmaxf(s[2][r], s[3][r]));
#pragma unroll
        for (int off = 1; off < 16; off <<= 1) mx = fmaxf(mx, __shfl_xor(mx, off));
        float mnew = fmaxf(*mr[r], mx);
        float f = __expf(*mr[r] - mnew);
        float sum = 0.f;
#pragma unroll
        for (int cg = 0; cg < 4; ++cg) {
          float p = __expf(s[cg][r] - mnew);
          s[cg][r] = p;
          sum += p;
        }
#pragma unroll
        for (int off = 1; off < 16; off <<= 1) sum += __shfl_xor(sum, off);
        *lsv[r] = *lsv[r] * f + sum;
        *mr[r] = mnew;
        *fc[r] = f;
      }
    }
    // write P (bf16) to per-wave LDS: Pl[w][q][key]
#pragma unroll
    for (int cg = 0; cg < 4; ++cg)
#pragma unroll
      for (int r = 0; r < 4; ++r)
        Pl[w][(l4 * 4 + r) * 72 + cg * 16 + l15] = f2b(s[cg][r]);
    // rescale O^T (column q = l15 is lane-uniform)
    float facq = redist16(fac0, fac1, fac2, fac3, l15);
#pragma unroll
    for (int mg = 0; mg < 4; ++mg)
#pragma unroll
      for (int r = 0; r < 4; ++r) o[mg][r] *= facq;
    // PV as ctx^T = V^T * P^T
#pragma unroll
    for (int ks = 0; ks < 2; ++ks) {
      bf16x8 bp = *(const bf16x8*)&Pl[w][l15 * 72 + ks * 32 + l4 * 8];
#pragma unroll
      for (int mg = 0; mg < 4; ++mg) {
        bf16x8 av = *(const bf16x8*)&Vt[(mg * 16 + l15) * 72 + ks * 32 + l4 * 8];
        o[mg] = __builtin_amdgcn_mfma_f32_16x16x32_bf16(av, bp, o[mg], 0, 0, 0);
      }
    }
  }
  // epilogue: divide by lsum(q), write ctx[b,s,h*64+d] bf16
  float lq = redist16(ls0, ls1, ls2, ls3, l15);
  float inv = 1.0f / lq;
  const long row = rowB + qt * 64 + w * 16 + l15;
#pragma unroll
  for (int mg = 0; mg < 4; ++mg)
#pragma unroll
    for (int r = 0; r < 4; ++r) {
      int d = h * 64 + mg * 16 + l4 * 4 + r;
      ctx[row * DD + d] = f2b(o[mg][r] * inv);
    }
}

// ---------------- workspace layout (bytes) ----------------
static const size_t OFF_WQKV = 0;          // 2304*768*2  = 3538944
static const size_t OFF_WO = 3538944;      // 768*768*2   = 1179648
static const size_t OFF_W1 = 4718592;      // 2048*768*2  = 3145728
static const size_t OFF_W2 = 7864320;      // 768*2048*2  = 3145728
static const size_t OFF_BQKV = 11010048;   // 2304*4
static const size_t OFF_N = 11019264;      // 4096*768*2  (reused for n2)
static const size_t OFF_QKV = 17310720;    // 4096*2304*2 (reused for h)
static const size_t OFF_CTX = 36185088;    // 4096*768*2
static const size_t OFF_X1 = 42476544;     // 4096*768*4
// total = 55059456 bytes

extern "C" void kernel_launch(void* const* d_in, const int* in_sizes, int n_in,
                              void* d_out, int out_size, void* d_ws, size_t ws_size,
                              hipStream_t stream) {
  (void)in_sizes; (void)n_in; (void)out_size; (void)ws_size;
  const float* x = (const float*)d_in[0];
  const int* mask = (const int*)d_in[1];
  const float* Wq = (const float*)d_in[2];
  const float* bq = (const float*)d_in[3];
  const float* Wk = (const float*)d_in[4];
  const float* bk = (const float*)d_in[5];
  const float* Wv = (const float*)d_in[6];
  const float* bv = (const float*)d_in[7];
  const float* Wo = (const float*)d_in[8];
  const float* bo = (const float*)d_in[9];
  const float* W1 = (const float*)d_in[10];
  const float* b1 = (const float*)d_in[11];
  const float* W2 = (const float*)d_in[12];
  const float* b2 = (const float*)d_in[13];
  const float* alpha = (const float*)d_in[14];
  const float* beta = (const float*)d_in[15];

  char* ws = (char*)d_ws;
  unsigned short* wqkv = (unsigned short*)(ws + OFF_WQKV);
  unsigned short* wo_b = (unsigned short*)(ws + OFF_WO);
  unsigned short* w1_b = (unsigned short*)(ws + OFF_W1);
  unsigned short* w2_b = (unsigned short*)(ws + OFF_W2);
  float* bqkv = (float*)(ws + OFF_BQKV);
  unsigned short* n_b = (unsigned short*)(ws + OFF_N);
  unsigned short* qkv_b = (unsigned short*)(ws + OFF_QKV);
  unsigned short* h_b = qkv_b;  // reuse after attention
  unsigned short* ctx_b = (unsigned short*)(ws + OFF_CTX);
  float* x1_f = (float*)(ws + OFF_X1);
  float* out_f = (float*)d_out;

  // weight conversions fp32->bf16
  cvt_bf16_k<<<576, 256, 0, stream>>>(Wq, wqkv);
  cvt_bf16_k<<<576, 256, 0, stream>>>(Wk, wqkv + 589824);
  cvt_bf16_k<<<576, 256, 0, stream>>>(Wv, wqkv + 1179648);
  cvt_bf16_k<<<576, 256, 0, stream>>>(Wo, wo_b);
  cvt_bf16_k<<<1536, 256, 0, stream>>>(W1, w1_b);
  cvt_bf16_k<<<1536, 256, 0, stream>>>(W2, w2_b);
  concat3_k<<<9, 256, 0, stream>>>(bq, bk, bv, bqkv);

  // LN1
  layernorm_k<<<4096, 64, 0, stream>>>(x, alpha, beta, n_b);
  // fused QKV GEMM: [4096,768] x [2304,768]^T -> [4096,2304] bf16
  gemm_bt<false, false, true><<<dim3(18, 32), 256, 0, stream>>>(
      n_b, wqkv, bqkv, nullptr, qkv_b, BSR, QKV_LD, DD);
  // attention
  attn_kernel<<<dim3(32, HH, 2), 256, 0, stream>>>(qkv_b, mask, ctx_b);
  // Wo GEMM + residual(x) -> x1 fp32
  gemm_bt<false, true, false><<<dim3(6, 32), 256, 0, stream>>>(
      ctx_b, wo_b, bo, x, x1_f, BSR, DD, DD);
  // LN2
  layernorm_k<<<4096, 64, 0, stream>>>(x1_f, alpha, beta, n_b);
  // FFN1 + relu -> h bf16
  gemm_bt<true, false, true><<<dim3(16, 32), 256, 0, stream>>>(
      n_b, w1_b, b1, nullptr, h_b, BSR, DFFF, DD);
  // FFN2 + residual(x1) -> out fp32
  gemm_bt<false, true, false><<<dim3(6, 32), 256, 0, stream>>>(
      h_b, w2_b, b2, x1_f, out_f, BSR, DD, DFFF);
}

// Round 2
// 223.160 us; speedup vs baseline: 1.3349x; 1.3349x over previous
//
#include <hip/hip_runtime.h>

// EncoderLayer: pre-norm MHA + FFN, B=2 S=2048 D=768 H=12 DFF=2048, fp32 I/O,
// bf16 MFMA internals. Pipeline:
//   cvt weights->bf16, LN1, QKV-GEMM(fused N=2304), flash-attn, Wo-GEMM+res,
//   LN2, FFN1-GEMM+relu, FFN2-GEMM+res -> d_out
#define SS   2048
#define DD   768
#define HH   12
#define DFFF 2048
#define BSR  4096      // B*S
#define QKV_LD 2304

typedef __attribute__((ext_vector_type(8))) short bf16x8;
typedef __attribute__((ext_vector_type(4))) float f32x4;

__device__ __forceinline__ unsigned short f2b(float f) {
  union { float f; unsigned u; } x; x.f = f;
  unsigned r = (x.u + 0x7FFFu + ((x.u >> 16) & 1u)) >> 16;
  return (unsigned short)r;
}

__device__ __forceinline__ unsigned pk2(float a, float b) {
  return (unsigned)f2b(a) | ((unsigned)f2b(b) << 16);
}

__device__ __forceinline__ void gload_lds16(const void* g, void* l) {
  __builtin_amdgcn_global_load_lds(
      (const __attribute__((address_space(1))) unsigned int*)g,
      (__attribute__((address_space(3))) unsigned int*)l,
      16, 0, 0);
}

// ---------------- fp32 -> bf16 convert (4 elems/thread) ----------------
__global__ __launch_bounds__(256) void cvt_bf16_k(const float* __restrict__ src,
                                                  unsigned short* __restrict__ dst) {
  long i = ((long)blockIdx.x * 256 + threadIdx.x) * 4;
  float4 v = *(const float4*)&src[i];
  uint2 pk;
  pk.x = (unsigned)f2b(v.x) | ((unsigned)f2b(v.y) << 16);
  pk.y = (unsigned)f2b(v.z) | ((unsigned)f2b(v.w) << 16);
  *(uint2*)&dst[i] = pk;
}

__global__ __launch_bounds__(256) void concat3_k(const float* __restrict__ a,
                                                 const float* __restrict__ b,
                                                 const float* __restrict__ c,
                                                 float* __restrict__ out) {
  int i = blockIdx.x * 256 + threadIdx.x;
  if (i < 768) out[i] = a[i];
  else if (i < 1536) out[i] = b[i - 768];
  else if (i < 2304) out[i] = c[i - 1536];
}

// ---------------- LayerNorm (torch semantics: ddof=1, eps on std) -------
__global__ __launch_bounds__(64) void layernorm_k(const float* __restrict__ x,
                                                  const float* __restrict__ alpha,
                                                  const float* __restrict__ beta,
                                                  unsigned short* __restrict__ outb) {
  const int row = blockIdx.x, lane = threadIdx.x;
  const float* xr = x + (long)row * DD;
  float4 v[3];
#pragma unroll
  for (int g = 0; g < 3; ++g) v[g] = *(const float4*)&xr[lane * 12 + g * 4];
  float sum = 0.f;
#pragma unroll
  for (int g = 0; g < 3; ++g) sum += v[g].x + v[g].y + v[g].z + v[g].w;
#pragma unroll
  for (int off = 1; off < 64; off <<= 1) sum += __shfl_xor(sum, off);
  float mu = sum * (1.0f / 768.0f);
  float ss = 0.f;
#pragma unroll
  for (int g = 0; g < 3; ++g) {
    float a0 = v[g].x - mu, a1 = v[g].y - mu, a2 = v[g].z - mu, a3 = v[g].w - mu;
    ss += a0 * a0 + a1 * a1 + a2 * a2 + a3 * a3;
  }
#pragma unroll
  for (int off = 1; off < 64; off <<= 1) ss += __shfl_xor(ss, off);
  float sd = sqrtf(ss * (1.0f / 767.0f));
  float inv = 1.0f / (sd + 1e-6f);
  unsigned short* orow = outb + (long)row * DD;
#pragma unroll
  for (int g = 0; g < 3; ++g) {
    float4 al = *(const float4*)&alpha[lane * 12 + g * 4];
    float4 be = *(const float4*)&beta[lane * 12 + g * 4];
    float o0 = al.x * (v[g].x - mu) * inv + be.x;
    float o1 = al.y * (v[g].y - mu) * inv + be.y;
    float o2 = al.z * (v[g].z - mu) * inv + be.z;
    float o3 = al.w * (v[g].w - mu) * inv + be.w;
    uint2 pk;
    pk.x = (unsigned)f2b(o0) | ((unsigned)f2b(o1) << 16);
    pk.y = (unsigned)f2b(o2) | ((unsigned)f2b(o3) << 16);
    *(uint2*)&orow[lane * 12 + g * 4] = pk;
  }
}

// ---------------- bf16 GEMM: C[M,N] = A[M,K] * W[N,K]^T (+bias,+res,relu) ----
// 128x128 tile, BK=64, 4 waves, global_load_lds staging (m97 structure).
template <bool RELU, bool RES, bool OUTB>
__global__ __launch_bounds__(256, 2) void gemm_bt(const unsigned short* __restrict__ A,
                                                  const unsigned short* __restrict__ W,
                                                  const float* __restrict__ bias,
                                                  const float* __restrict__ res,
                                                  void* __restrict__ outp,
                                                  int M, int N, int K) {
  __shared__ __align__(16) unsigned short As[128 * 64];
  __shared__ __align__(16) unsigned short Bs[128 * 64];
  const int t = threadIdx.x;
  const int lane = t & 63;
  const int w = t >> 6;
  const int wr = w >> 1, wc = w & 1;
  const int l15 = lane & 15, l4 = lane >> 4;
  const long brow = (long)blockIdx.y * 128;
  const long bcol = (long)blockIdx.x * 128;
  f32x4 acc[4][4] = {};
  const int r0 = t >> 3;        // 0..31
  const int c8 = (t & 7) * 8;   // 0..56

  for (int k0 = 0; k0 < K; k0 += 64) {
    __syncthreads();
#pragma unroll
    for (int p = 0; p < 4; ++p) {
      gload_lds16(&A[(brow + p * 32 + r0) * (long)K + k0 + c8],
                  (char*)As + p * 4096 + w * 1024);
      gload_lds16(&W[(bcol + p * 32 + r0) * (long)K + k0 + c8],
                  (char*)Bs + p * 4096 + w * 1024);
    }
    __syncthreads();
#pragma unroll
    for (int ks = 0; ks < 2; ++ks) {
      bf16x8 a[4], b[4];
#pragma unroll
      for (int m = 0; m < 4; ++m)
        a[m] = *(const bf16x8*)&As[(wr * 64 + m * 16 + l15) * 64 + ks * 32 + l4 * 8];
#pragma unroll
      for (int n = 0; n < 4; ++n)
        b[n] = *(const bf16x8*)&Bs[(wc * 64 + n * 16 + l15) * 64 + ks * 32 + l4 * 8];
#pragma unroll
      for (int m = 0; m < 4; ++m)
#pragma unroll
        for (int n = 0; n < 4; ++n)
          acc[m][n] = __builtin_amdgcn_mfma_f32_16x16x32_bf16(a[m], b[n], acc[m][n], 0, 0, 0);
    }
  }
#pragma unroll
  for (int n = 0; n < 4; ++n) {
    const long col = bcol + wc * 64 + n * 16 + l15;
    const float bv = bias[col];
#pragma unroll
    for (int m = 0; m < 4; ++m) {
      const long row0 = brow + wr * 64 + m * 16 + l4 * 4;
#pragma unroll
      for (int r = 0; r < 4; ++r) {
        float v = acc[m][n][r] + bv;
        if (RELU) v = fmaxf(v, 0.0f);
        long o = (row0 + r) * (long)N + col;
        if (RES) v += res[o];
        if (OUTB) ((unsigned short*)outp)[o] = f2b(v);
        else ((float*)outp)[o] = v;
      }
    }
  }
}

// ---------------- flash attention v2: swapped QK^T, LDS dbuf, swizzles ------
// one (b,h,64-q-tile) per block, 4 waves x 16 q-rows, KV tile = 64 keys.
__global__ __launch_bounds__(256, 2) void attn_kernel(const unsigned short* __restrict__ qkv,
                                                      const int* __restrict__ mask,
                                                      unsigned short* __restrict__ ctx) {
  __shared__ __align__(16) unsigned short Ks[2][64 * 64];  // K [key][d], XOR-swz
  __shared__ __align__(16) unsigned short Vt[2][64 * 64];  // V^T [d][key], XOR-swz
  __shared__ __align__(16) unsigned short Pl[4][16 * 72];  // per-wave P^T [q][key]
  const int t = threadIdx.x, lane = t & 63, w = t >> 6;
  const int l15 = lane & 15, l4 = lane >> 4;
  // XCD-chunked swizzle: 32 q-tiles of one (b,h) land on one XCD's L2
  const int u = (blockIdx.x & 7) * 96 + (blockIdx.x >> 3);
  const int qt = u & 31;
  const int h = (u >> 5) % 12;
  const int b = u / 384;
  const long rowB = (long)b * SS;

  // Q fragment (B operand): lane l15 = q, elems d = ks*32 + l4*8 + j
  bf16x8 aq[2];
#pragma unroll
  for (int ks = 0; ks < 2; ++ks)
    aq[ks] = *(const bf16x8*)&qkv[(rowB + qt * 64 + w * 16 + l15) * QKV_LD +
                                  h * 64 + ks * 32 + l4 * 8];

  // K staging constants (gload_lds linear dest; swizzle folded into global src)
  const int krow = w * 8 + (lane >> 3);                    // +p*32
  const int kdo = ((((lane & 7) << 4) ^ ((lane >> 3) << 4)) >> 1);  // shorts
  // V load constants
  const int vkey = t >> 3;                                 // 0..31 (+p*32)
  const int vd0 = (t & 7) * 8;
  const int vpar = vkey & 1;
  const int kread_swz = (l15 & 7) << 4;

  uint4 vreg[2];
  f32x4 o[4] = {};
  float mrun = -1e30f, lsum = 0.f;

  // ---- prologue: stage tile 0 ----
#pragma unroll
  for (int p = 0; p < 2; ++p)
    gload_lds16(&qkv[(rowB + p * 32 + krow) * QKV_LD + 768 + h * 64 + kdo],
                (char*)Ks[0] + p * 4096 + w * 1024);
#pragma unroll
  for (int p = 0; p < 2; ++p)
    vreg[p] = *(const uint4*)&qkv[(rowB + p * 32 + vkey) * QKV_LD + 1536 + h * 64 + vd0];
  // transpose-write V tile 0
#pragma unroll
  for (int p = 0; p < 2; ++p) {
    unsigned own[4] = {vreg[p].x, vreg[p].y, vreg[p].z, vreg[p].w};
#pragma unroll
    for (int j = 0; j < 4; ++j) {
      unsigned part = __shfl_xor(own[j], 8);
      unsigned val = vpar ? ((part >> 16) | (own[j] & 0xffff0000u))
                          : ((own[j] & 0xffffu) | (part << 16));
      int d = vd0 + 2 * j + vpar;
      int swz = (((2 * j + vpar) ^ (t & 7)) & 7) << 4;
      int kp = p * 16 + (vkey >> 1);
      *(unsigned*)((char*)Vt[0] + d * 128 + ((kp * 4) ^ swz)) = val;
    }
  }
  __syncthreads();

  for (int kb = 0; kb < 32; ++kb) {
    const int bi = kb & 1;
    // ---- prefetch next tile (K direct-to-LDS, V to regs) ----
    if (kb < 31) {
#pragma unroll
      for (int p = 0; p < 2; ++p)
        gload_lds16(&qkv[(rowB + (kb + 1) * 64 + p * 32 + krow) * QKV_LD + 768 + h * 64 + kdo],
                    (char*)Ks[bi ^ 1] + p * 4096 + w * 1024);
#pragma unroll
      for (int p = 0; p < 2; ++p)
        vreg[p] = *(const uint4*)&qkv[(rowB + (kb + 1) * 64 + p * 32 + vkey) * QKV_LD +
                                      1536 + h * 64 + vd0];
    }
    // ---- QK^T (swapped): S^T[key][q], col=l15=q, row=key=cg*16+l4*4+r ----
    f32x4 s[4] = {};
#pragma unroll
    for (int ks = 0; ks < 2; ++ks)
#pragma unroll
      for (int cg = 0; cg < 4; ++cg) {
        bf16x8 ak = *(const bf16x8*)((const char*)Ks[bi] + (cg * 16 + l15) * 128 +
                                     ((ks * 64 + l4 * 16) ^ kread_swz));
        s[cg] = __builtin_amdgcn_mfma_f32_16x16x32_bf16(ak, aq[ks], s[cg], 0, 0, 0);
      }
    // ---- scale + mask + online softmax (per-q stats, q = l15) ----
    float mx = -1e30f;
#pragma unroll
    for (int cg = 0; cg < 4; ++cg) {
      int4 mm = *(const int4*)&mask[b * SS + kb * 64 + cg * 16 + l4 * 4];
      int mi[4] = {mm.x, mm.y, mm.z, mm.w};
#pragma unroll
      for (int r = 0; r < 4; ++r) {
        s[cg][r] = s[cg][r] * 0.125f + (mi[r] ? 0.f : -1e9f);
        mx = fmaxf(mx, s[cg][r]);
      }
    }
    mx = fmaxf(mx, __shfl_xor(mx, 16));
    mx = fmaxf(mx, __shfl_xor(mx, 32));
    const float mnew = fmaxf(mrun, mx);
    const float fac = __expf(mrun - mnew);
    float sum = 0.f;
#pragma unroll
    for (int cg = 0; cg < 4; ++cg)
#pragma unroll
      for (int r = 0; r < 4; ++r) {
        float p = __expf(s[cg][r] - mnew);
        s[cg][r] = p;
        sum += p;
      }
    sum += __shfl_xor(sum, 16);
    sum += __shfl_xor(sum, 32);
    lsum = lsum * fac + sum;
    mrun = mnew;
    // ---- P^T -> per-wave LDS as [q][key] (packed b32 writes) ----
#pragma unroll
    for (int cg = 0; cg < 4; ++cg) {
      unsigned* pw = (unsigned*)&Pl[w][l15 * 72 + cg * 16 + l4 * 4];
      pw[0] = pk2(s[cg][0], s[cg][1]);
      pw[1] = pk2(s[cg][2], s[cg][3]);
    }
    // ---- rescale O (fac is per-q = lane-uniform across l4) ----
#pragma unroll
    for (int mg = 0; mg < 4; ++mg)
#pragma unroll
      for (int r = 0; r < 4; ++r) o[mg][r] *= fac;
    // ---- PV: ctx^T[d][q] = V^T . P^T ----
#pragma unroll
    for (int ks = 0; ks < 2; ++ks) {
      bf16x8 bp = *(const bf16x8*)&Pl[w][l15 * 72 + ks * 32 + l4 * 8];
#pragma unroll
      for (int mg = 0; mg < 4; ++mg) {
        const int dv = mg * 16 + l15;
        const int sv = ((dv ^ (dv >> 3)) & 7) << 4;
        bf16x8 av = *(const bf16x8*)((const char*)Vt[bi] + dv * 128 +
                                     ((ks * 64 + l4 * 16) ^ sv));
        o[mg] = __builtin_amdgcn_mfma_f32_16x16x32_bf16(av, bp, o[mg], 0, 0, 0);
      }
    }
    // ---- write next V tile (vreg landed under compute) ----
    if (kb < 31) {
#pragma unroll
      for (int p = 0; p < 2; ++p) {
        unsigned own[4] = {vreg[p].x, vreg[p].y, vreg[p].z, vreg[p].w};
#pragma unroll
        for (int j = 0; j < 4; ++j) {
          unsigned part = __shfl_xor(own[j], 8);
          unsigned val = vpar ? ((part >> 16) | (own[j] & 0xffff0000u))
                              : ((own[j] & 0xffffu) | (part << 16));
          int d = vd0 + 2 * j + vpar;
          int swz = (((2 * j + vpar) ^ (t & 7)) & 7) << 4;
          int kp = p * 16 + (vkey >> 1);
          *(unsigned*)((char*)Vt[bi ^ 1] + d * 128 + ((kp * 4) ^ swz)) = val;
        }
      }
    }
    __syncthreads();
  }
  // ---- epilogue: O^T regs hold col q=l15, row d=mg*16+l4*4+r ----
  const float inv = 1.0f / lsum;
  const long obase = (rowB + qt * 64 + w * 16 + l15) * DD + h * 64 + l4 * 4;
#pragma unroll
  for (int mg = 0; mg < 4; ++mg) {
    *(unsigned*)&ctx[obase + mg * 16] = pk2(o[mg][0] * inv, o[mg][1] * inv);
    *(unsigned*)&ctx[obase + mg * 16 + 2] = pk2(o[mg][2] * inv, o[mg][3] * inv);
  }
}

// ---------------- workspace layout (bytes) ----------------
static const size_t OFF_WQKV = 0;          // 2304*768*2  = 3538944
static const size_t OFF_WO = 3538944;      // 768*768*2   = 1179648
static const size_t OFF_W1 = 4718592;      // 2048*768*2  = 3145728
static const size_t OFF_W2 = 7864320;      // 768*2048*2  = 3145728
static const size_t OFF_BQKV = 11010048;   // 2304*4
static const size_t OFF_N = 11019264;      // 4096*768*2  (reused for n2)
static const size_t OFF_QKV = 17310720;    // 4096*2304*2 (reused for h)
static const size_t OFF_CTX = 36185088;    // 4096*768*2
static const size_t OFF_X1 = 42476544;     // 4096*768*4
// total = 55059456 bytes

extern "C" void kernel_launch(void* const* d_in, const int* in_sizes, int n_in,
                              void* d_out, int out_size, void* d_ws, size_t ws_size,
                              hipStream_t stream) {
  (void)in_sizes; (void)n_in; (void)out_size; (void)ws_size;
  const float* x = (const float*)d_in[0];
  const int* mask = (const int*)d_in[1];
  const float* Wq = (const float*)d_in[2];
  const float* bq = (const float*)d_in[3];
  const float* Wk = (const float*)d_in[4];
  const float* bk = (const float*)d_in[5];
  const float* Wv = (const float*)d_in[6];
  const float* bv = (const float*)d_in[7];
  const float* Wo = (const float*)d_in[8];
  const float* bo = (const float*)d_in[9];
  const float* W1 = (const float*)d_in[10];
  const float* b1 = (const float*)d_in[11];
  const float* W2 = (const float*)d_in[12];
  const float* b2 = (const float*)d_in[13];
  const float* alpha = (const float*)d_in[14];
  const float* beta = (const float*)d_in[15];

  char* ws = (char*)d_ws;
  unsigned short* wqkv = (unsigned short*)(ws + OFF_WQKV);
  unsigned short* wo_b = (unsigned short*)(ws + OFF_WO);
  unsigned short* w1_b = (unsigned short*)(ws + OFF_W1);
  unsigned short* w2_b = (unsigned short*)(ws + OFF_W2);
  float* bqkv = (float*)(ws + OFF_BQKV);
  unsigned short* n_b = (unsigned short*)(ws + OFF_N);
  unsigned short* qkv_b = (unsigned short*)(ws + OFF_QKV);
  unsigned short* h_b = qkv_b;  // reuse after attention
  unsigned short* ctx_b = (unsigned short*)(ws + OFF_CTX);
  float* x1_f = (float*)(ws + OFF_X1);
  float* out_f = (float*)d_out;

  // weight conversions fp32->bf16
  cvt_bf16_k<<<576, 256, 0, stream>>>(Wq, wqkv);
  cvt_bf16_k<<<576, 256, 0, stream>>>(Wk, wqkv + 589824);
  cvt_bf16_k<<<576, 256, 0, stream>>>(Wv, wqkv + 1179648);
  cvt_bf16_k<<<576, 256, 0, stream>>>(Wo, wo_b);
  cvt_bf16_k<<<1536, 256, 0, stream>>>(W1, w1_b);
  cvt_bf16_k<<<1536, 256, 0, stream>>>(W2, w2_b);
  concat3_k<<<9, 256, 0, stream>>>(bq, bk, bv, bqkv);

  // LN1
  layernorm_k<<<4096, 64, 0, stream>>>(x, alpha, beta, n_b);
  // fused QKV GEMM: [4096,768] x [2304,768]^T -> [4096,2304] bf16
  gemm_bt<false, false, true><<<dim3(18, 32), 256, 0, stream>>>(
      n_b, wqkv, bqkv, nullptr, qkv_b, BSR, QKV_LD, DD);
  // attention
  attn_kernel<<<768, 256, 0, stream>>>(qkv_b, mask, ctx_b);
  // Wo GEMM + residual(x) -> x1 fp32
  gemm_bt<false, true, false><<<dim3(6, 32), 256, 0, stream>>>(
      ctx_b, wo_b, bo, x, x1_f, BSR, DD, DD);
  // LN2
  layernorm_k<<<4096, 64, 0, stream>>>(x1_f, alpha, beta, n_b);
  // FFN1 + relu -> h bf16
  gemm_bt<true, false, true><<<dim3(16, 32), 256, 0, stream>>>(
      n_b, w1_b, b1, nullptr, h_b, BSR, DFFF, DD);
  // FFN2 + residual(x1) -> out fp32
  gemm_bt<false, true, false><<<dim3(6, 32), 256, 0, stream>>>(
      h_b, w2_b, b2, x1_f, out_f, BSR, DD, DFFF);
}